// Round 1
// baseline (654.526 us; speedup 1.0000x reference)
//
#include <hip/hip_runtime.h>

#define N_TOT   32768
#define K_CODES 1024
#define D_DIM   256
#define DECAY_F 0.99f
#define OMD_F   0.01f      // 1 - decay
#define EPS_F   1e-5f

// ---------------- ws layout (float offsets) ----------------
#define WS_COUNTS      0          // 1024 floats
#define WS_DW          1024       // 262144 floats
#define WS_LOSS        263168     // 256 floats
#define WS_CSUM        263424     // 1 float
#define WS_ZERO_FLOATS 263425     // memset range [0, this)
#define WS_ENORM       263680     // 1024 floats
#define WS_IDX         264704     // 32768 ints

// ---------------- out layout (float offsets) ----------------
#define OUT_ZQ    0               // 8388608
#define OUT_LOSS  8388608         // 1
#define OUT_IDX   8388609         // 32768 (indices as float)
#define OUT_EMB   8421377         // 262144
#define OUT_CS    8683521         // 1024
#define OUT_EMAW  8684545         // 262144

// ======================= kernel 1: ||e_k||^2 =======================
__global__ __launch_bounds__(64)
void enorm_kernel(const float* __restrict__ emb, float* __restrict__ enorm) {
    const int k = blockIdx.x;
    const int t = threadIdx.x;                      // 0..63
    const float4 v = *(const float4*)(emb + (size_t)k * D_DIM + t * 4);
    float s = v.x * v.x + v.y * v.y + v.z * v.z + v.w * v.w;
    #pragma unroll
    for (int off = 32; off > 0; off >>= 1) s += __shfl_down(s, off);
    if (t == 0) enorm[k] = s;
}

// ======================= kernel 2: argmin over codes =======================
// Block: 256 threads (tx=tid&15 codes dim, ty=tid>>4 rows dim)
// Tile: 64 rows x 64 codes, D chunked by 128. 4x4 register tile/thread.
// LDS: xs[64][128] + es[64][128] fp32 = 65536 B, XOR-swizzled float4 slots.
__global__ __launch_bounds__(256, 2)
void argmin_kernel(const float* __restrict__ z, const float* __restrict__ emb,
                   const float* __restrict__ enorm,
                   int* __restrict__ idx_out, float* __restrict__ idxf_out) {
    __shared__ float lds[16384];                    // xs = lds[0..8191], es = lds[8192..]
    float* xs = lds;
    float* es = lds + 8192;

    const int tid = threadIdx.x;
    const int tx  = tid & 15;
    const int ty  = tid >> 4;
    const int row0 = blockIdx.x * 64;

    // swizzle masks for the 4 rows / 4 codes this thread touches
    int xm[4], em[4];
    #pragma unroll
    for (int i = 0; i < 4; ++i) { xm[i] = (ty + 16 * i) & 31; em[i] = (tx + 16 * i) & 31; }

    float bestd[4];
    int   besti[4];
    #pragma unroll
    for (int i = 0; i < 4; ++i) { bestd[i] = 3.4e38f; besti[i] = 0; }

    for (int kt = 0; kt < 16; ++kt) {
        float acc[4][4];
        #pragma unroll
        for (int i = 0; i < 4; ++i)
            #pragma unroll
            for (int j = 0; j < 4; ++j) acc[i][j] = 0.0f;

        for (int dc = 0; dc < 2; ++dc) {
            __syncthreads();
            // stage x tile and e tile (swizzled float4 slots)
            #pragma unroll
            for (int l = 0; l < 8; ++l) {
                const int s = tid + l * 256;        // 0..2047
                const int r = s >> 5;               // row in tile (0..63)
                const int p = s & 31;               // float4 slot in 128-float chunk
                const int sw = (p ^ (r & 31)) << 2; // swizzled float offset
                const float4 xv = *(const float4*)(z   + (size_t)(row0 + r)    * D_DIM + dc * 128 + p * 4);
                const float4 ev = *(const float4*)(emb + (size_t)(kt * 64 + r) * D_DIM + dc * 128 + p * 4);
                *(float4*)&xs[r * 128 + sw] = xv;
                *(float4*)&es[r * 128 + sw] = ev;
            }
            __syncthreads();

            #pragma unroll 8
            for (int dq = 0; dq < 32; ++dq) {
                float4 xv[4], ev[4];
                #pragma unroll
                for (int i = 0; i < 4; ++i)
                    xv[i] = *(const float4*)&xs[(ty + 16 * i) * 128 + ((dq ^ xm[i]) << 2)];
                #pragma unroll
                for (int j = 0; j < 4; ++j)
                    ev[j] = *(const float4*)&es[(tx + 16 * j) * 128 + ((dq ^ em[j]) << 2)];
                #pragma unroll
                for (int i = 0; i < 4; ++i)
                    #pragma unroll
                    for (int j = 0; j < 4; ++j) {
                        acc[i][j] = fmaf(xv[i].x, ev[j].x, acc[i][j]);
                        acc[i][j] = fmaf(xv[i].y, ev[j].y, acc[i][j]);
                        acc[i][j] = fmaf(xv[i].z, ev[j].z, acc[i][j]);
                        acc[i][j] = fmaf(xv[i].w, ev[j].w, acc[i][j]);
                    }
            }
        }
        // distance + running argmin (codes ascending -> strict < keeps first occurrence)
        #pragma unroll
        for (int j = 0; j < 4; ++j) {
            const int c = kt * 64 + tx + 16 * j;
            const float en = enorm[c];
            #pragma unroll
            for (int i = 0; i < 4; ++i) {
                const float dist = fmaf(-2.0f, acc[i][j], en);
                if (dist < bestd[i] || (dist == bestd[i] && c < besti[i])) {
                    bestd[i] = dist; besti[i] = c;
                }
            }
        }
    }

    // reduce across the 16 tx lanes (within wave), first-occurrence tie-break
    #pragma unroll
    for (int m = 1; m < 16; m <<= 1) {
        #pragma unroll
        for (int i = 0; i < 4; ++i) {
            const float od = __shfl_xor(bestd[i], m);
            const int   oi = __shfl_xor(besti[i], m);
            if (od < bestd[i] || (od == bestd[i] && oi < besti[i])) {
                bestd[i] = od; besti[i] = oi;
            }
        }
    }
    if (tx == 0) {
        #pragma unroll
        for (int i = 0; i < 4; ++i) {
            const int r = row0 + ty + 16 * i;
            idx_out[r]  = besti[i];
            idxf_out[r] = (float)besti[i];
        }
    }
}

// ============ kernel 3: gather z_q, loss partials, counts, dw scatter ============
__global__ __launch_bounds__(256)
void gather_kernel(const float* __restrict__ z, const float* __restrict__ emb,
                   const int* __restrict__ idx, float* __restrict__ out_zq,
                   float* __restrict__ counts, float* __restrict__ dw,
                   float* __restrict__ lossbuf) {
    const int tid  = threadIdx.x;
    const int lane = tid & 63;
    const int n    = blockIdx.x * 4 + (tid >> 6);
    const int k    = idx[n];

    const float4 e4 = *(const float4*)(emb + (size_t)k * D_DIM + lane * 4);
    const float4 x4 = *(const float4*)(z   + (size_t)n * D_DIM + lane * 4);
    *(float4*)(out_zq + (size_t)n * D_DIM + lane * 4) = e4;

    const float dx = e4.x - x4.x, dy = e4.y - x4.y, dz = e4.z - x4.z, dw_ = e4.w - x4.w;
    float s = dx * dx + dy * dy + dz * dz + dw_ * dw_;
    #pragma unroll
    for (int off = 32; off > 0; off >>= 1) s += __shfl_down(s, off);
    if (lane == 0) {
        atomicAdd(&lossbuf[n & 255], s);
        atomicAdd(&counts[k], 1.0f);
    }
    float* dwp = dw + (size_t)k * D_DIM + lane * 4;
    atomicAdd(dwp + 0, x4.x);
    atomicAdd(dwp + 1, x4.y);
    atomicAdd(dwp + 2, x4.z);
    atomicAdd(dwp + 3, x4.w);
}

// ============ kernel 4a: new_cluster_size, n-sum, loss finalize ============
__global__ __launch_bounds__(256)
void update_cs_kernel(const float* __restrict__ ema_cs, const float* __restrict__ counts,
                      const float* __restrict__ lossbuf,
                      float* __restrict__ out_cs, float* __restrict__ out_loss,
                      float* __restrict__ csum) {
    __shared__ float red[256];
    const int t = threadIdx.x;
    float local = 0.0f;
    #pragma unroll
    for (int i = 0; i < 4; ++i) {
        const int k = t + 256 * i;
        const float c = DECAY_F * ema_cs[k] + OMD_F * counts[k];
        out_cs[k] = c;
        local += c;
    }
    red[t] = local; __syncthreads();
    #pragma unroll
    for (int off = 128; off > 0; off >>= 1) {
        if (t < off) red[t] += red[t + off];
        __syncthreads();
    }
    if (t == 0) csum[0] = red[0];
    __syncthreads();
    red[t] = lossbuf[t]; __syncthreads();
    #pragma unroll
    for (int off = 128; off > 0; off >>= 1) {
        if (t < off) red[t] += red[t + off];
        __syncthreads();
    }
    if (t == 0) out_loss[0] = 1.25f * red[0] / 8388608.0f;   // (1+0.25)*mean over N*D
}

// ============ kernel 4b: new_ema_w and new_embedding ============
__global__ __launch_bounds__(256)
void update_w_kernel(const float* __restrict__ ema_w, const float* __restrict__ dw,
                     const float* __restrict__ out_cs, const float* __restrict__ csum,
                     float* __restrict__ out_emb, float* __restrict__ out_emaw) {
    const int g = blockIdx.x * 256 + threadIdx.x;   // float4 slot, 0..65535
    const int k = g >> 6;                           // 64 float4 per code row
    const float n_total = csum[0];
    const float cs = (out_cs[k] + EPS_F) / (n_total + K_CODES * EPS_F) * n_total;

    const float4 w4 = *(const float4*)(ema_w + (size_t)g * 4);
    const float4 d4 = *(const float4*)(dw    + (size_t)g * 4);
    float4 nw, ne;
    nw.x = DECAY_F * w4.x + OMD_F * d4.x;
    nw.y = DECAY_F * w4.y + OMD_F * d4.y;
    nw.z = DECAY_F * w4.z + OMD_F * d4.z;
    nw.w = DECAY_F * w4.w + OMD_F * d4.w;
    ne.x = nw.x / cs; ne.y = nw.y / cs; ne.z = nw.z / cs; ne.w = nw.w / cs;
    *(float4*)(out_emaw + (size_t)g * 4) = nw;
    *(float4*)(out_emb  + (size_t)g * 4) = ne;
}

// ======================= launcher =======================
extern "C" void kernel_launch(void* const* d_in, const int* in_sizes, int n_in,
                              void* d_out, int out_size, void* d_ws, size_t ws_size,
                              hipStream_t stream) {
    const float* z      = (const float*)d_in[0];   // z_e          [32768, 256]
    const float* emb    = (const float*)d_in[1];   // embedding    [1024, 256]
    const float* ema_cs = (const float*)d_in[2];   // ema_cluster_size [1024]
    const float* ema_w  = (const float*)d_in[3];   // ema_w        [1024, 256]

    float* out   = (float*)d_out;
    float* ws    = (float*)d_ws;

    float* counts  = ws + WS_COUNTS;
    float* dw      = ws + WS_DW;
    float* lossbuf = ws + WS_LOSS;
    float* csum    = ws + WS_CSUM;
    float* enorm   = ws + WS_ENORM;
    int*   idx     = (int*)(ws + WS_IDX);

    float* out_zq   = out + OUT_ZQ;
    float* out_loss = out + OUT_LOSS;
    float* out_idxf = out + OUT_IDX;
    float* out_emb  = out + OUT_EMB;
    float* out_cs   = out + OUT_CS;
    float* out_emaw = out + OUT_EMAW;

    // zero accumulators (counts, dw, lossbuf, csum are contiguous at ws start)
    hipMemsetAsync(d_ws, 0, (size_t)WS_ZERO_FLOATS * sizeof(float), stream);

    enorm_kernel<<<K_CODES, 64, 0, stream>>>(emb, enorm);
    argmin_kernel<<<N_TOT / 64, 256, 0, stream>>>(z, emb, enorm, idx, out_idxf);
    gather_kernel<<<N_TOT / 4, 256, 0, stream>>>(z, emb, idx, out_zq, counts, dw, lossbuf);
    update_cs_kernel<<<1, 256, 0, stream>>>(ema_cs, counts, lossbuf, out_cs, out_loss, csum);
    update_w_kernel<<<(K_CODES * D_DIM / 4) / 256, 256, 0, stream>>>(
        ema_w, dw, out_cs, csum, out_emb, out_emaw);
}

// Round 2
// 320.692 us; speedup vs baseline: 2.0410x; 2.0410x over previous
//
#include <hip/hip_runtime.h>

#define DECAY_F 0.99f
#define OMD_F   0.01f
#define EPS_F   1e-5f

typedef __attribute__((ext_vector_type(8))) __bf16 bf16x8;
typedef __attribute__((ext_vector_type(4))) float  f32x4;

// ---------------- ws layout (byte offsets) ----------------
#define WSB_COUNTS   0          // 1024 f32 (4096 B)   [memset]
#define WSB_LOSS     4096       // 256 f32  (1024 B)   [memset]
#define WSB_CSUM     5120       // 1 f32               [memset]
#define WSB_MEMSET   5632       // memset range [0, 5632)
#define WSB_ENORM    5632       // 1024 f32 (4096 B)
#define WSB_IDX      9728       // 32768 i32 (131072 B)
#define WSB_EHI      140800     // 262144 ushort (524288 B)
#define WSB_ELO      665088     // 262144 ushort (524288 B)

// ---------------- out layout (float offsets) ----------------
#define OUT_ZQ    0
#define OUT_LOSS  8388608
#define OUT_IDX   8388609
#define OUT_EMB   8421377
#define OUT_CS    8683521
#define OUT_EMAW  8684545

// ---------- bf16 split helpers (RNE, no NaN inputs) ----------
__device__ __forceinline__ unsigned short f2bf(float x) {
    unsigned u = __builtin_bit_cast(unsigned, x);
    u += 0x7fffu + ((u >> 16) & 1u);
    return (unsigned short)(u >> 16);
}
__device__ __forceinline__ float bf2f(unsigned short h) {
    return __builtin_bit_cast(float, (unsigned)h << 16);
}
__device__ __forceinline__ void split8(const float4 a, const float4 b,
                                       uint4& hi, uint4& lo) {
    float f[8] = {a.x, a.y, a.z, a.w, b.x, b.y, b.z, b.w};
    unsigned short h[8], l[8];
    #pragma unroll
    for (int i = 0; i < 8; ++i) {
        h[i] = f2bf(f[i]);
        l[i] = f2bf(f[i] - bf2f(h[i]));
    }
    hi.x = (unsigned)h[0] | ((unsigned)h[1] << 16);
    hi.y = (unsigned)h[2] | ((unsigned)h[3] << 16);
    hi.z = (unsigned)h[4] | ((unsigned)h[5] << 16);
    hi.w = (unsigned)h[6] | ((unsigned)h[7] << 16);
    lo.x = (unsigned)l[0] | ((unsigned)l[1] << 16);
    lo.y = (unsigned)l[2] | ((unsigned)l[3] << 16);
    lo.z = (unsigned)l[4] | ((unsigned)l[5] << 16);
    lo.w = (unsigned)l[6] | ((unsigned)l[7] << 16);
}

// ============ kernel 0: split embedding to bf16 hi/lo ============
__global__ __launch_bounds__(256)
void esplit_kernel(const float* __restrict__ emb,
                   unsigned short* __restrict__ e_hi, unsigned short* __restrict__ e_lo) {
    const int g = blockIdx.x * 256 + threadIdx.x;      // 8-float segment, 0..32767
    const float4 a = *(const float4*)(emb + (size_t)g * 8);
    const float4 b = *(const float4*)(emb + (size_t)g * 8 + 4);
    uint4 hi, lo;
    split8(a, b, hi, lo);
    *(uint4*)(e_hi + (size_t)g * 8) = hi;
    *(uint4*)(e_lo + (size_t)g * 8) = lo;
}

// ============ kernel 1: ||e_k||^2 (fp32 exact) ============
__global__ __launch_bounds__(64)
void enorm_kernel(const float* __restrict__ emb, float* __restrict__ enorm) {
    const int k = blockIdx.x;
    const int t = threadIdx.x;
    const float4 v = *(const float4*)(emb + (size_t)k * 256 + t * 4);
    float s = v.x * v.x + v.y * v.y + v.z * v.z + v.w * v.w;
    #pragma unroll
    for (int off = 32; off > 0; off >>= 1) s += __shfl_down(s, off);
    if (t == 0) enorm[k] = s;
}

// ============ kernel 2: MFMA argmin (4-term bf16 split GEMM) ============
// Block 256 thr = 4 waves (2x2). Block tile: 64 rows x 256 codes (loop ct=4 over 1024).
// Wave tile 32x128 = 2x8 grid of 16x16x32 MFMAs. BK=32, 8 k-chunks over D=256.
// 4 operand combos (AhBh, AhBl, AlBh, AlBl) share one fp32 acc -> fp32-class dot.
// LDS 40 KB: Ah/Al [64][32] bf16, Bh/Bl [256][32] bf16, XOR slot swizzle.
__global__ __launch_bounds__(256, 2)
void argmin_kernel(const float* __restrict__ z,
                   const unsigned short* __restrict__ e_hi,
                   const unsigned short* __restrict__ e_lo,
                   const float* __restrict__ enorm,
                   int* __restrict__ idx_out, float* __restrict__ idxf_out) {
    __shared__ unsigned short Ah[64 * 32], Al[64 * 32];
    __shared__ unsigned short Bh[256 * 32], Bl[256 * 32];

    const int tid  = threadIdx.x;
    const int lane = tid & 63;
    const int wv   = tid >> 6;
    const int wy   = wv >> 1, wx = wv & 1;
    const int tx   = lane & 15, quad = lane >> 4;
    const int row0 = blockIdx.x * 64;

    // staging assignments
    const int rA = tid >> 2, gA = tid & 3;                       // A: 1 segment/thread
    const float* zA = z + (size_t)(row0 + rA) * 256 + gA * 8;
    const int offA = rA * 32 + ((gA ^ (rA & 3)) << 3);

    float bestd[2][4];
    int   besti[2][4];
    #pragma unroll
    for (int i = 0; i < 2; ++i)
        #pragma unroll
        for (int r = 0; r < 4; ++r) { bestd[i][r] = 3.4e38f; besti[i][r] = 0; }

    // precompute frag read offsets
    int offAf[2], offBf[8];
    #pragma unroll
    for (int i = 0; i < 2; ++i) {
        const int rt = wy * 32 + i * 16 + tx;
        offAf[i] = rt * 32 + (((quad ^ (rt & 3))) << 3);
    }
    #pragma unroll
    for (int j = 0; j < 8; ++j) {
        const int cb = wx * 128 + j * 16 + tx;
        offBf[j] = cb * 32 + (((quad ^ (cb & 3))) << 3);
    }

    for (int ct = 0; ct < 4; ++ct) {
        f32x4 acc[2][8];
        #pragma unroll
        for (int i = 0; i < 2; ++i)
            #pragma unroll
            for (int j = 0; j < 8; ++j) acc[i][j] = (f32x4)0.0f;

        for (int kc = 0; kc < 8; ++kc) {
            __syncthreads();
            // ---- stage A (fp32 -> hi/lo split in regs) ----
            {
                const float4 a0 = *(const float4*)(zA + kc * 32);
                const float4 a1 = *(const float4*)(zA + kc * 32 + 4);
                uint4 hi, lo;
                split8(a0, a1, hi, lo);
                *(uint4*)(Ah + offA) = hi;
                *(uint4*)(Al + offA) = lo;
            }
            // ---- stage B (pre-split bf16 from ws) ----
            #pragma unroll
            for (int t = 0; t < 4; ++t) {
                const int s  = tid + t * 256;
                const int cB = s >> 2, gB = s & 3;
                const size_t gb = (size_t)(ct * 256 + cB) * 256 + kc * 32 + gB * 8;
                const int offB = cB * 32 + ((gB ^ (cB & 3)) << 3);
                *(uint4*)(Bh + offB) = *(const uint4*)(e_hi + gb);
                *(uint4*)(Bl + offB) = *(const uint4*)(e_lo + gb);
            }
            __syncthreads();

            // ---- fragment loads (each tile read once) ----
            bf16x8 af[2][2], bfr[2][8];
            #pragma unroll
            for (int i = 0; i < 2; ++i) {
                af[0][i] = __builtin_bit_cast(bf16x8, *(const uint4*)(Ah + offAf[i]));
                af[1][i] = __builtin_bit_cast(bf16x8, *(const uint4*)(Al + offAf[i]));
            }
            #pragma unroll
            for (int j = 0; j < 8; ++j) {
                bfr[0][j] = __builtin_bit_cast(bf16x8, *(const uint4*)(Bh + offBf[j]));
                bfr[1][j] = __builtin_bit_cast(bf16x8, *(const uint4*)(Bl + offBf[j]));
            }
            // ---- 64 MFMAs: 4 combos x 2x8 tiles ----
            #pragma unroll
            for (int ao = 0; ao < 2; ++ao)
                #pragma unroll
                for (int bo = 0; bo < 2; ++bo)
                    #pragma unroll
                    for (int j = 0; j < 8; ++j)
                        #pragma unroll
                        for (int i = 0; i < 2; ++i)
                            acc[i][j] = __builtin_amdgcn_mfma_f32_16x16x32_bf16(
                                af[ao][i], bfr[bo][j], acc[i][j], 0, 0, 0);
        }

        // ---- distances + running argmin ----
        #pragma unroll
        for (int j = 0; j < 8; ++j) {
            const int col = ct * 256 + wx * 128 + j * 16 + tx;
            const float en = enorm[col];
            #pragma unroll
            for (int i = 0; i < 2; ++i)
                #pragma unroll
                for (int r = 0; r < 4; ++r) {
                    const float d = fmaf(-2.0f, acc[i][j][r], en);
                    if (d < bestd[i][r] || (d == bestd[i][r] && col < besti[i][r])) {
                        bestd[i][r] = d; besti[i][r] = col;
                    }
                }
        }
    }

    // ---- butterfly reduce over the 16 tx lanes of each quad ----
    #pragma unroll
    for (int m = 1; m < 16; m <<= 1) {
        #pragma unroll
        for (int i = 0; i < 2; ++i)
            #pragma unroll
            for (int r = 0; r < 4; ++r) {
                const float od = __shfl_xor(bestd[i][r], m);
                const int   oi = __shfl_xor(besti[i][r], m);
                if (od < bestd[i][r] || (od == bestd[i][r] && oi < besti[i][r])) {
                    bestd[i][r] = od; besti[i][r] = oi;
                }
            }
    }

    // ---- merge the two wx halves via LDS ----
    __syncthreads();                       // all MFMA-tile reads done; safe to reuse
    float* mg_d = (float*)Ah;              // [2][64]
    int*   mg_i = (int*)Ah + 128;          // [2][64]
    if (tx == 0) {
        #pragma unroll
        for (int i = 0; i < 2; ++i)
            #pragma unroll
            for (int r = 0; r < 4; ++r) {
                const int rb = wy * 32 + i * 16 + quad * 4 + r;
                mg_d[wx * 64 + rb] = bestd[i][r];
                mg_i[wx * 64 + rb] = besti[i][r];
            }
    }
    __syncthreads();
    if (tid < 64) {
        float d0 = mg_d[tid];      int i0 = mg_i[tid];
        const float d1 = mg_d[64 + tid]; const int i1 = mg_i[64 + tid];
        if (d1 < d0 || (d1 == d0 && i1 < i0)) { d0 = d1; i0 = i1; }
        idx_out[row0 + tid]  = i0;
        idxf_out[row0 + tid] = (float)i0;
    }
}

// ============ kernel 3: gather z_q, loss partials, counts ============
__global__ __launch_bounds__(256)
void gather_kernel(const float* __restrict__ z, const float* __restrict__ emb,
                   const int* __restrict__ idx, float* __restrict__ out_zq,
                   float* __restrict__ counts, float* __restrict__ lossbuf) {
    const int tid  = threadIdx.x;
    const int lane = tid & 63;
    const int n    = blockIdx.x * 4 + (tid >> 6);
    const int k    = idx[n];

    const float4 e4 = *(const float4*)(emb + (size_t)k * 256 + lane * 4);
    const float4 x4 = *(const float4*)(z   + (size_t)n * 256 + lane * 4);
    *(float4*)(out_zq + (size_t)n * 256 + lane * 4) = e4;

    const float dx = e4.x - x4.x, dy = e4.y - x4.y, dz = e4.z - x4.z, dw_ = e4.w - x4.w;
    float s = dx * dx + dy * dy + dz * dz + dw_ * dw_;
    #pragma unroll
    for (int off = 32; off > 0; off >>= 1) s += __shfl_down(s, off);
    if (lane == 0) {
        atomicAdd(&lossbuf[n & 255], s);
        atomicAdd(&counts[k], 1.0f);
    }
}

// ============ kernel 4: new_cluster_size, n-sum, loss finalize ============
__global__ __launch_bounds__(256)
void update_cs_kernel(const float* __restrict__ ema_cs, const float* __restrict__ counts,
                      const float* __restrict__ lossbuf,
                      float* __restrict__ out_cs, float* __restrict__ out_loss,
                      float* __restrict__ csum) {
    __shared__ float red[256];
    const int t = threadIdx.x;
    float local = 0.0f;
    #pragma unroll
    for (int i = 0; i < 4; ++i) {
        const int k = t + 256 * i;
        const float c = DECAY_F * ema_cs[k] + OMD_F * counts[k];
        out_cs[k] = c;
        local += c;
    }
    red[t] = local; __syncthreads();
    #pragma unroll
    for (int off = 128; off > 0; off >>= 1) {
        if (t < off) red[t] += red[t + off];
        __syncthreads();
    }
    if (t == 0) csum[0] = red[0];
    __syncthreads();
    red[t] = lossbuf[t]; __syncthreads();
    #pragma unroll
    for (int off = 128; off > 0; off >>= 1) {
        if (t < off) red[t] += red[t + off];
        __syncthreads();
    }
    if (t == 0) out_loss[0] = 1.25f * red[0] / 8388608.0f;
}

// ============ kernel 5: per-code dw reduction + EMA-w/embedding epilogue ============
// One block per code; LDS match list; zero global atomics.
__global__ __launch_bounds__(256)
void dw_update_kernel(const float* __restrict__ z, const int* __restrict__ idx,
                      const float* __restrict__ ema_w, const float* __restrict__ out_cs,
                      const float* __restrict__ csum,
                      float* __restrict__ out_emb, float* __restrict__ out_emaw) {
    __shared__ int lrows[4096];
    __shared__ int lcnt;
    const int k = blockIdx.x;
    const int t = threadIdx.x;
    if (t == 0) lcnt = 0;
    __syncthreads();
    #pragma unroll 4
    for (int c = 0; c < 128; ++c) {
        const int r = c * 256 + t;
        if (idx[r] == k) {
            const int p = atomicAdd(&lcnt, 1);
            if (p < 4096) lrows[p] = r;
        }
    }
    __syncthreads();
    int m = lcnt; if (m > 4096) m = 4096;
    float s = 0.0f;
    for (int j = 0; j < m; ++j)
        s += z[(size_t)lrows[j] * 256 + t];

    const float n_total = csum[0];
    const float cs = (out_cs[k] + EPS_F) / (n_total + 1024.0f * EPS_F) * n_total;
    const float nw = DECAY_F * ema_w[(size_t)k * 256 + t] + OMD_F * s;
    out_emaw[(size_t)k * 256 + t] = nw;
    out_emb [(size_t)k * 256 + t] = nw / cs;
}

// ======================= launcher =======================
extern "C" void kernel_launch(void* const* d_in, const int* in_sizes, int n_in,
                              void* d_out, int out_size, void* d_ws, size_t ws_size,
                              hipStream_t stream) {
    const float* z      = (const float*)d_in[0];
    const float* emb    = (const float*)d_in[1];
    const float* ema_cs = (const float*)d_in[2];
    const float* ema_w  = (const float*)d_in[3];

    float* out = (float*)d_out;
    char*  wsb = (char*)d_ws;

    float*          counts  = (float*)(wsb + WSB_COUNTS);
    float*          lossbuf = (float*)(wsb + WSB_LOSS);
    float*          csum    = (float*)(wsb + WSB_CSUM);
    float*          enorm   = (float*)(wsb + WSB_ENORM);
    int*            idx     = (int*)(wsb + WSB_IDX);
    unsigned short* e_hi    = (unsigned short*)(wsb + WSB_EHI);
    unsigned short* e_lo    = (unsigned short*)(wsb + WSB_ELO);

    float* out_zq   = out + OUT_ZQ;
    float* out_loss = out + OUT_LOSS;
    float* out_idxf = out + OUT_IDX;
    float* out_emb  = out + OUT_EMB;
    float* out_cs   = out + OUT_CS;
    float* out_emaw = out + OUT_EMAW;

    hipMemsetAsync(d_ws, 0, WSB_MEMSET, stream);

    esplit_kernel<<<128, 256, 0, stream>>>(emb, e_hi, e_lo);
    enorm_kernel<<<1024, 64, 0, stream>>>(emb, enorm);
    argmin_kernel<<<512, 256, 0, stream>>>(z, e_hi, e_lo, enorm, idx, out_idxf);
    gather_kernel<<<8192, 256, 0, stream>>>(z, emb, idx, out_zq, counts, lossbuf);
    update_cs_kernel<<<1, 256, 0, stream>>>(ema_cs, counts, lossbuf, out_cs, out_loss, csum);
    dw_update_kernel<<<1024, 256, 0, stream>>>(z, idx, ema_w, out_cs, csum,
                                               out_emb, out_emaw);
}